// Round 18
// baseline (40.867 us; speedup 1.0000x reference)
//
#include <hip/hip_runtime.h>
#include <math.h>

// Problem constants
#define BB 8
#define CC 3
#define DD 24
#define HH 128
#define WW 128
#define HW (HH * WW)
#define OCC 16
#define HOUT 126
#define WOUT 126

typedef short bf16x8 __attribute__((ext_vector_type(8)));   // 4 VGPR
typedef float f32x4 __attribute__((ext_vector_type(4)));
typedef unsigned int u32;
typedef u32 u32x4 __attribute__((ext_vector_type(4)));

#define MFMA(a, b, c) __builtin_amdgcn_mfma_f32_16x16x32_bf16((a), (b), (c), 0, 0, 0)
// Pack the top halves of two f32 (a=even slot, c=odd slot) into one dword:
// result = (a>>16) | (c & 0xffff0000)  ==  v_perm_b32(hi=c, lo=a, 0x07060302)
#define PKHI(a, c) __builtin_amdgcn_perm((c), (a), 0x07060302u)

// Issue the 8 raw fp32 loads of one depth-plane's im2col slots (no pack).
__device__ __forceinline__ void load_raw(const float* __restrict__ xp,
                                         const int (&voff)[8], u32 (&u)[8]) {
#pragma unroll
  for (int j = 0; j < 8; ++j) u[j] = __float_as_uint(xp[voff[j]]);
}

// Pack 8 raw fp32 into ONE truncated-bf16 fragment: 4 v_perm_b32 total.
// (r18: x is single-term; the w side carries the split residual.)
__device__ __forceinline__ void pack_hi(const u32 (&u)[8], bf16x8& fh) {
  u32x4 hd;
#pragma unroll
  for (int p = 0; p < 4; ++p) hd[p] = PKHI(u[2 * p], u[2 * p + 1]);
  fh = __builtin_bit_cast(bf16x8, hd);
}

// One dz step (software-pipelined): FIRST issue plane-pnext loads into upre
// (consumed next step -> a full step of issue distance), THEN pack plane
// dz+2 (loaded last step) into fc, then 6 MFMAs in TWO independent chains
// (hi-weight chain + lo-weight chain, 3 deep each), merge, running min.
__device__ __forceinline__ void dz_step(const float* __restrict__ xb, int pnext,
                                        const int (&voff)[8],
                                        const bf16x8 (&waH)[3], const bf16x8 (&waL)[3],
                                        u32 (&upack)[8], u32 (&upre)[8],
                                        bf16x8& fa, bf16x8& fb, bf16x8& fc,
                                        f32x4& mn) {
  load_raw(xb + (size_t)pnext * HW, voff, upre);
  pack_hi(upack, fc);
  f32x4 a0 = {0.f, 0.f, 0.f, 0.f};
  f32x4 a1 = {0.f, 0.f, 0.f, 0.f};
  a0 = MFMA(waH[0], fa, a0); a1 = MFMA(waL[0], fa, a1);
  a0 = MFMA(waH[1], fb, a0); a1 = MFMA(waL[1], fb, a1);
  a0 = MFMA(waH[2], fc, a0); a1 = MFMA(waL[2], fc, a1);
  mn.x = fminf(mn.x, a0.x + a1.x);
  mn.y = fminf(mn.y, a0.y + a1.y);
  mn.z = fminf(mn.z, a0.z + a1.z);
  mn.w = fminf(mn.w, a0.w + a1.w);
}

// 256-thread blocks = 4 independent waves, wave wv handles w-tile
// wti = blockIdx.z*4+wv. Implicit-GEMM per wave: C[oc=16][px=16] via
// mfma_f32_16x16x32_bf16, A = weights (oc x K, TWO-term RTN split hi+lo,
// built once in prologue), B = im2col (K x px, single-term TRUNC bf16 ->
// pack = 4 perms/step). y = x_t*(w_hi+w_lo): error ~ x-trunc ~2^-8 rel
// (measured analog r17: 2e-3 from one ~2^-9 source; threshold 6.5e-3).
// K-tile t = kd-plane, k_local = c*9+kh*3+kw (27 real + 5 pad; pads zeroed
// on A side). Plane rotation F0..F2 reuses 2/3 fragments per dz; raw
// double-buffer U0/U1 covers load latency. C/D: col=lane&15=pixel,
// row=(lane>>4)*4+reg=oc (m89-verified, r15-validated).
__global__ __launch_bounds__(256) void conv_min_softmax_mfma(
    const float* __restrict__ x, const float* __restrict__ wt,
    float* __restrict__ out) {
  const int tid = threadIdx.x;
  const int lane = tid & 63;
  const int wv = tid >> 6;            // wave id 0..3
  const int q15 = lane & 15;          // pixel (B col) and oc (A row)
  const int g = lane >> 4;            // k-slot group
  const int b = blockIdx.x;
  const int h = blockIdx.y;
  const int wti = blockIdx.z * 4 + wv;
  const int w0 = (wti == 7) ? 110 : wti * 16;  // overlap last tile (no OOB)

  // Per-lane k-slot decode: k_local = g*8+j -> (c,kh,kw); pads -> offset 0.
  int voff[8];
#pragma unroll
  for (int j = 0; j < 8; ++j) {
    const int kl = g * 8 + j;
    if (kl < 27) {
      const int c = kl / 9, kh = (kl % 9) / 3, kw = kl % 3;
      voff[j] = c * DD * HW + kh * WW + (w0 + q15 + kw);
    } else {
      voff[j] = 0;  // finite dummy; A-side weight is 0 for pad slots
    }
  }

  // Weight fragments (A), per kd-tile t: RTN hi + RTN residual lo, pads = 0.
  bf16x8 waH[3], waL[3];
#pragma unroll
  for (int t = 0; t < 3; ++t) {
    u32 uh[8], ul[8];
#pragma unroll
    for (int j = 0; j < 8; ++j) {
      const int kl = g * 8 + j;
      float v = 0.f;
      if (kl < 27) {
        const int c = kl / 9, kh = (kl % 9) / 3, kw = kl % 3;
        v = wt[q15 * 81 + c * 27 + t * 9 + kh * 3 + kw];
      }
      const u32 ub = __float_as_uint(v);
      const u32 rh = ub + 0x7fffu + ((ub >> 16) & 1u);  // RTN-even (top half)
      uh[j] = rh;
      const float hi = __uint_as_float(rh & 0xffff0000u);
      const float lo = v - hi;                          // exact residual
      const u32 lb = __float_as_uint(lo);
      ul[j] = lb + 0x7fffu + ((lb >> 16) & 1u);         // RTN of residual
    }
    u32x4 hd, ld;
#pragma unroll
    for (int p = 0; p < 4; ++p) {
      hd[p] = PKHI(uh[2 * p], uh[2 * p + 1]);
      ld[p] = PKHI(ul[2 * p], ul[2 * p + 1]);
    }
    waH[t] = __builtin_bit_cast(bf16x8, hd);
    waL[t] = __builtin_bit_cast(bf16x8, ld);
  }

  const float* xb = x + ((size_t)b * CC * DD) * HW + (size_t)h * WW;

  // Prologue: planes 0,1 packed immediately; plane 2 raw in U0.
  u32 u0[8], u1[8];
  bf16x8 f0, f1, f2;
  load_raw(xb + (size_t)0 * HW, voff, u0);
  load_raw(xb + (size_t)1 * HW, voff, u1);
  pack_hi(u0, f0);
  pack_hi(u1, f1);
  load_raw(xb + (size_t)2 * HW, voff, u0);

  f32x4 mn = {INFINITY, INFINITY, INFINITY, INFINITY};

  // dz = 0..17: period-6 rotation (U parity x F rotation), runtime loop.
#pragma clang loop unroll(disable)
  for (int dzb = 0; dzb < 18; dzb += 6) {
    dz_step(xb, dzb + 3, voff, waH, waL, u0, u1, f0, f1, f2, mn);
    dz_step(xb, dzb + 4, voff, waH, waL, u1, u0, f1, f2, f0, mn);
    dz_step(xb, dzb + 5, voff, waH, waL, u0, u1, f2, f0, f1, mn);
    dz_step(xb, dzb + 6, voff, waH, waL, u1, u0, f0, f1, f2, mn);
    dz_step(xb, dzb + 7, voff, waH, waL, u0, u1, f1, f2, f0, mn);
    dz_step(xb, dzb + 8, voff, waH, waL, u1, u0, f2, f0, f1, mn);
  }
  // Tail dz = 18..21 (prefetch clamped to plane 23).
  dz_step(xb, 21, voff, waH, waL, u0, u1, f0, f1, f2, mn);
  dz_step(xb, 22, voff, waH, waL, u1, u0, f1, f2, f0, mn);
  dz_step(xb, 23, voff, waH, waL, u0, u1, f2, f0, f1, mn);
  dz_step(xb, 23, voff, waH, waL, u1, u0, f0, f1, f2, mn);

  // Softmax over oc for this lane's pixel: 4 in-lane regs (oc = g*4+r) +
  // lanes sharing q15 across g (xor 16, 32).
  float mx = fmaxf(fmaxf(mn.x, mn.y), fmaxf(mn.z, mn.w));
  mx = fmaxf(mx, __shfl_xor(mx, 16));
  mx = fmaxf(mx, __shfl_xor(mx, 32));
  const float e0 = __expf(mn.x - mx);
  const float e1 = __expf(mn.y - mx);
  const float e2 = __expf(mn.z - mx);
  const float e3 = __expf(mn.w - mx);
  float s = (e0 + e1) + (e2 + e3);
  s += __shfl_xor(s, 16);
  s += __shfl_xor(s, 32);
  const float inv = 1.f / s;

  // Store: out[b][oc = g*4+r][h][w0+q15]; 16 consecutive pixels per (g,r).
  float* ob = out + (((size_t)(b * OCC + g * 4) * HOUT + h) * WOUT) + w0 + q15;
  const size_t os = (size_t)HOUT * WOUT;
  ob[0 * os] = e0 * inv;
  ob[1 * os] = e1 * inv;
  ob[2 * os] = e2 * inv;
  ob[3 * os] = e3 * inv;
}

extern "C" void kernel_launch(void* const* d_in, const int* in_sizes, int n_in,
                              void* d_out, int out_size, void* d_ws, size_t ws_size,
                              hipStream_t stream) {
  const float* x = (const float*)d_in[0];
  const float* wt = (const float*)d_in[1];
  float* out = (float*)d_out;

  dim3 grid(BB, HOUT, 2);   // b (XCD-pinned), h, w-tile-pair
  dim3 block(256, 1, 1);    // 4 waves = 4 w-tiles
  conv_min_softmax_mfma<<<grid, block, 0, stream>>>(x, wt, out);
}

// Round 19
// 35.480 us; speedup vs baseline: 1.1518x; 1.1518x over previous
//
#include <hip/hip_runtime.h>
#include <math.h>

// Problem constants
#define BB 8
#define CC 3
#define DD 24
#define HH 128
#define WW 128
#define HW (HH * WW)
#define OCC 16
#define HOUT 126
#define WOUT 126

typedef short bf16x8 __attribute__((ext_vector_type(8)));   // 4 VGPR
typedef float f32x4 __attribute__((ext_vector_type(4)));
typedef unsigned int u32;
typedef u32 u32x4 __attribute__((ext_vector_type(4)));

#define MFMA(a, b, c) __builtin_amdgcn_mfma_f32_16x16x32_bf16((a), (b), (c), 0, 0, 0)
// Pack the top halves of two f32 (a=even slot, c=odd slot) into one dword:
// result = (a>>16) | (c & 0xffff0000)  ==  v_perm_b32(hi=c, lo=a, 0x07060302)
#define PKHI(a, c) __builtin_amdgcn_perm((c), (a), 0x07060302u)

// Issue the 8 raw fp32 loads of one depth-plane's im2col slots (no pack).
__device__ __forceinline__ void load_raw(const float* __restrict__ xp,
                                         const int (&voff)[8], u32 (&u)[8]) {
#pragma unroll
  for (int j = 0; j < 8; ++j) u[j] = __float_as_uint(xp[voff[j]]);
}

// Pack 8 raw fp32 into split-bf16 fragments: hi = truncate (1 perm/pair),
// lo = residual x - trunc(x) truncated to bf16 (and+sub per value + perm).
__device__ __forceinline__ void pack_frag(const u32 (&u)[8], bf16x8& fh,
                                          bf16x8& fl) {
  u32x4 hd, ld;
#pragma unroll
  for (int p = 0; p < 4; ++p) {
    const u32 a = u[2 * p], c = u[2 * p + 1];
    hd[p] = PKHI(a, c);
    const float la = __uint_as_float(a) - __uint_as_float(a & 0xffff0000u);
    const float lc = __uint_as_float(c) - __uint_as_float(c & 0xffff0000u);
    ld[p] = PKHI(__float_as_uint(la), __float_as_uint(lc));
  }
  fh = __builtin_bit_cast(bf16x8, hd);
  fl = __builtin_bit_cast(bf16x8, ld);
}

// One dz step. ROUND 19 (r17 + ONE change): pack FIRST, then reload the
// SAME raw buffer with plane dz+4 — the anti-dependency (load rewrites the
// regs pack just read) keeps order, and the prefetch distance doubles to 2
// full steps (~400 issue-cycles at observed residency) with the same 2
// buffers and zero extra instructions. r18's regression showed distance-1
// is latency-exposed once pack shrinks; r17's math (x split hi/lo 2-term,
// w RTN 1-term, 6 MFMA) is restored verbatim (proven 36.2 us / 1.95e-3).
__device__ __forceinline__ void dz_step(const float* __restrict__ xb, int pnext,
                                        const int (&voff)[8],
                                        const bf16x8 (&wa)[3],
                                        u32 (&ubuf)[8],
                                        bf16x8& ah, bf16x8& al,
                                        bf16x8& bh, bf16x8& bl,
                                        bf16x8& ch, bf16x8& cl, f32x4& mn) {
  pack_frag(ubuf, ch, cl);                       // consume plane dz+2
  load_raw(xb + (size_t)pnext * HW, voff, ubuf); // prefetch plane dz+4
  f32x4 acc = {0.f, 0.f, 0.f, 0.f};
  acc = MFMA(wa[0], ah, acc); acc = MFMA(wa[0], al, acc);
  acc = MFMA(wa[1], bh, acc); acc = MFMA(wa[1], bl, acc);
  acc = MFMA(wa[2], ch, acc); acc = MFMA(wa[2], cl, acc);
  mn.x = fminf(mn.x, acc.x);
  mn.y = fminf(mn.y, acc.y);
  mn.z = fminf(mn.z, acc.z);
  mn.w = fminf(mn.w, acc.w);
}

// 256-thread blocks = 4 independent waves, wave wv handles w-tile
// wti = blockIdx.z*4+wv. Implicit-GEMM per wave: C[oc=16][px=16] via
// mfma_f32_16x16x32_bf16, A = weights (oc x K, RTN-bf16 single term),
// B = im2col (K x px, split-bf16 hi+lo), K-tile t = kd-plane,
// k_local = c*9+kh*3+kw (27 real + 5 pad; pads zeroed on A side).
// Plane rotation F0..F2 reuses 2/3 fragments per dz; raw double-buffer
// U0/U1 (parity dz&1) holds plane dz+2 at step entry. C/D layout:
// col=lane&15=pixel, row=(lane>>4)*4+reg=oc (m89-verified, r15-validated).
__global__ __launch_bounds__(256) void conv_min_softmax_mfma(
    const float* __restrict__ x, const float* __restrict__ wt,
    float* __restrict__ out) {
  const int tid = threadIdx.x;
  const int lane = tid & 63;
  const int wv = tid >> 6;            // wave id 0..3
  const int q15 = lane & 15;          // pixel (B col) and oc (A row)
  const int g = lane >> 4;            // k-slot group
  const int b = blockIdx.x;
  const int h = blockIdx.y;
  const int wti = blockIdx.z * 4 + wv;
  const int w0 = (wti == 7) ? 110 : wti * 16;  // overlap last tile (no OOB)

  // Per-lane k-slot decode: k_local = g*8+j -> (c,kh,kw); pads -> offset 0.
  int voff[8];
#pragma unroll
  for (int j = 0; j < 8; ++j) {
    const int kl = g * 8 + j;
    if (kl < 27) {
      const int c = kl / 9, kh = (kl % 9) / 3, kw = kl % 3;
      voff[j] = c * DD * HW + kh * WW + (w0 + q15 + kw);
    } else {
      voff[j] = 0;  // finite dummy; A-side weight is 0 for pad slots
    }
  }

  // Weight fragments (A), per kd-tile t: single-term RTN bf16, pads = 0.
  bf16x8 wa[3];
#pragma unroll
  for (int t = 0; t < 3; ++t) {
    u32 u[8];
#pragma unroll
    for (int j = 0; j < 8; ++j) {
      const int kl = g * 8 + j;
      float v = 0.f;
      if (kl < 27) {
        const int c = kl / 9, kh = (kl % 9) / 3, kw = kl % 3;
        v = wt[q15 * 81 + c * 27 + t * 9 + kh * 3 + kw];
      }
      const u32 ub = __float_as_uint(v);
      u[j] = ub + 0x7fffu + ((ub >> 16) & 1u);  // round-to-nearest-even bf16
    }
    u32x4 hd;
#pragma unroll
    for (int p = 0; p < 4; ++p) hd[p] = PKHI(u[2 * p], u[2 * p + 1]);
    wa[t] = __builtin_bit_cast(bf16x8, hd);
  }

  const float* xb = x + ((size_t)b * CC * DD) * HW + (size_t)h * WW;

  // Prologue: planes 0,1 packed immediately; planes 2,3 raw in U0,U1.
  u32 u0[8], u1[8];
  bf16x8 f0h, f0l, f1h, f1l, f2h, f2l;
  load_raw(xb + (size_t)0 * HW, voff, u0);
  load_raw(xb + (size_t)1 * HW, voff, u1);
  pack_frag(u0, f0h, f0l);
  pack_frag(u1, f1h, f1l);
  load_raw(xb + (size_t)2 * HW, voff, u0);
  load_raw(xb + (size_t)3 * HW, voff, u1);

  f32x4 mn = {INFINITY, INFINITY, INFINITY, INFINITY};

  // dz = 0..17: period-6 (U parity x F rotation); step dz packs plane dz+2
  // and prefetches plane dz+4.
#pragma clang loop unroll(disable)
  for (int dzb = 0; dzb < 18; dzb += 6) {
    dz_step(xb, dzb + 4, voff, wa, u0, f0h, f0l, f1h, f1l, f2h, f2l, mn);
    dz_step(xb, dzb + 5, voff, wa, u1, f1h, f1l, f2h, f2l, f0h, f0l, mn);
    dz_step(xb, dzb + 6, voff, wa, u0, f2h, f2l, f0h, f0l, f1h, f1l, mn);
    dz_step(xb, dzb + 7, voff, wa, u1, f0h, f0l, f1h, f1l, f2h, f2l, mn);
    dz_step(xb, dzb + 8, voff, wa, u0, f1h, f1l, f2h, f2l, f0h, f0l, mn);
    dz_step(xb, dzb + 9, voff, wa, u1, f2h, f2l, f0h, f0l, f1h, f1l, mn);
  }
  // Tail dz = 18..21 (prefetch clamped to plane 23).
  dz_step(xb, 22, voff, wa, u0, f0h, f0l, f1h, f1l, f2h, f2l, mn);
  dz_step(xb, 23, voff, wa, u1, f1h, f1l, f2h, f2l, f0h, f0l, mn);
  dz_step(xb, 23, voff, wa, u0, f2h, f2l, f0h, f0l, f1h, f1l, mn);
  dz_step(xb, 23, voff, wa, u1, f0h, f0l, f1h, f1l, f2h, f2l, mn);

  // Softmax over oc for this lane's pixel: 4 in-lane regs (oc = g*4+r) +
  // lanes sharing q15 across g (xor 16, 32).
  float mx = fmaxf(fmaxf(mn.x, mn.y), fmaxf(mn.z, mn.w));
  mx = fmaxf(mx, __shfl_xor(mx, 16));
  mx = fmaxf(mx, __shfl_xor(mx, 32));
  const float e0 = __expf(mn.x - mx);
  const float e1 = __expf(mn.y - mx);
  const float e2 = __expf(mn.z - mx);
  const float e3 = __expf(mn.w - mx);
  float s = (e0 + e1) + (e2 + e3);
  s += __shfl_xor(s, 16);
  s += __shfl_xor(s, 32);
  const float inv = 1.f / s;

  // Store: out[b][oc = g*4+r][h][w0+q15]; 16 consecutive pixels per (g,r).
  float* ob = out + (((size_t)(b * OCC + g * 4) * HOUT + h) * WOUT) + w0 + q15;
  const size_t os = (size_t)HOUT * WOUT;
  ob[0 * os] = e0 * inv;
  ob[1 * os] = e1 * inv;
  ob[2 * os] = e2 * inv;
  ob[3 * os] = e3 * inv;
}

extern "C" void kernel_launch(void* const* d_in, const int* in_sizes, int n_in,
                              void* d_out, int out_size, void* d_ws, size_t ws_size,
                              hipStream_t stream) {
  const float* x = (const float*)d_in[0];
  const float* wt = (const float*)d_in[1];
  float* out = (float*)d_out;

  dim3 grid(BB, HOUT, 2);   // b (XCD-pinned), h, w-tile-pair
  dim3 block(256, 1, 1);    // 4 waves = 4 w-tiles
  conv_min_softmax_mfma<<<grid, block, 0, stream>>>(x, wt, out);
}

// Round 20
// 33.837 us; speedup vs baseline: 1.2077x; 1.0486x over previous
//
#include <hip/hip_runtime.h>
#include <math.h>

// Problem constants
#define BB 8
#define CC 3
#define DD 24
#define HH 128
#define WW 128
#define HW (HH * WW)
#define OCC 16
#define HOUT 126
#define WOUT 126

typedef short bf16x8 __attribute__((ext_vector_type(8)));   // 4 VGPR
typedef float f32x4 __attribute__((ext_vector_type(4)));
typedef unsigned int u32;
typedef u32 u32x4 __attribute__((ext_vector_type(4)));

#define MFMA(a, b, c) __builtin_amdgcn_mfma_f32_16x16x32_bf16((a), (b), (c), 0, 0, 0)
// Pack the top halves of two f32 (a=even slot, c=odd slot) into one dword:
// result = (a>>16) | (c & 0xffff0000)  ==  v_perm_b32(hi=c, lo=a, 0x07060302)
#define PKHI(a, c) __builtin_amdgcn_perm((c), (a), 0x07060302u)

// Issue the 8 raw fp32 loads of one depth-plane's im2col slots (no pack).
__device__ __forceinline__ void load_raw(const float* __restrict__ xp,
                                         const int (&voff)[8], u32 (&u)[8]) {
#pragma unroll
  for (int j = 0; j < 8; ++j) u[j] = __float_as_uint(xp[voff[j]]);
}

// Pack 8 raw fp32 into ONE truncated-bf16 fragment: 4 v_perm_b32 total.
// (x is single-term; the w side carries the split residual — r18 numerics,
// measured absmax 1.95e-3.)
__device__ __forceinline__ void pack_hi(const u32 (&u)[8], bf16x8& fh) {
  u32x4 hd;
#pragma unroll
  for (int p = 0; p < 4; ++p) hd[p] = PKHI(u[2 * p], u[2 * p + 1]);
  fh = __builtin_bit_cast(bf16x8, hd);
}

// One dz step. ROUND 20 = r19's proven distance-2 schedule (pack FIRST,
// then reload the SAME buffer -> anti-dependency keeps order, prefetch
// distance = 2 full steps) + r18's lean numerics (x trunc 1-term -> pack is
// 4 perms; w 2-term RTN split carries the residual, prologue-only cost).
// 6 MFMAs in two independent 3-deep chains (hi-w, lo-w), zero-init from a
// persistent zero register (no per-step v_mov), merge + running min.
__device__ __forceinline__ void dz_step(const float* __restrict__ xb, int pnext,
                                        const int (&voff)[8],
                                        const bf16x8 (&waH)[3], const bf16x8 (&waL)[3],
                                        u32 (&ubuf)[8],
                                        bf16x8& fa, bf16x8& fb, bf16x8& fc,
                                        const f32x4& z4, f32x4& mn) {
  pack_hi(ubuf, fc);                             // consume plane dz+2
  load_raw(xb + (size_t)pnext * HW, voff, ubuf); // prefetch plane dz+4
  f32x4 a0 = MFMA(waH[0], fa, z4);
  f32x4 a1 = MFMA(waL[0], fa, z4);
  a0 = MFMA(waH[1], fb, a0);
  a1 = MFMA(waL[1], fb, a1);
  a0 = MFMA(waH[2], fc, a0);
  a1 = MFMA(waL[2], fc, a1);
  mn.x = fminf(mn.x, a0.x + a1.x);
  mn.y = fminf(mn.y, a0.y + a1.y);
  mn.z = fminf(mn.z, a0.z + a1.z);
  mn.w = fminf(mn.w, a0.w + a1.w);
}

// 256-thread blocks = 4 independent waves, wave wv handles w-tile
// wti = blockIdx.z*4+wv. Implicit-GEMM per wave: C[oc=16][px=16] via
// mfma_f32_16x16x32_bf16, A = weights (oc x K, TWO-term RTN split hi+lo,
// built once in prologue), B = im2col (K x px, single-term TRUNC bf16,
// 4-perm pack). K-tile t = kd-plane, k_local = c*9+kh*3+kw (27 real +
// 5 pad; pads zeroed on A side). Plane rotation F0..F2 reuses 2/3
// fragments per dz; raw double-buffer U0/U1 (parity) holds plane dz+2 at
// step entry, reloaded with dz+4 after pack (distance-2). C/D layout:
// col=lane&15=pixel, row=(lane>>4)*4+reg=oc (m89-verified, r15-validated).
__global__ __launch_bounds__(256) void conv_min_softmax_mfma(
    const float* __restrict__ x, const float* __restrict__ wt,
    float* __restrict__ out) {
  const int tid = threadIdx.x;
  const int lane = tid & 63;
  const int wv = tid >> 6;            // wave id 0..3
  const int q15 = lane & 15;          // pixel (B col) and oc (A row)
  const int g = lane >> 4;            // k-slot group
  const int b = blockIdx.x;
  const int h = blockIdx.y;
  const int wti = blockIdx.z * 4 + wv;
  const int w0 = (wti == 7) ? 110 : wti * 16;  // overlap last tile (no OOB)

  // Per-lane k-slot decode: k_local = g*8+j -> (c,kh,kw); pads -> offset 0.
  int voff[8];
#pragma unroll
  for (int j = 0; j < 8; ++j) {
    const int kl = g * 8 + j;
    if (kl < 27) {
      const int c = kl / 9, kh = (kl % 9) / 3, kw = kl % 3;
      voff[j] = c * DD * HW + kh * WW + (w0 + q15 + kw);
    } else {
      voff[j] = 0;  // finite dummy; A-side weight is 0 for pad slots
    }
  }

  // Weight fragments (A), per kd-tile t: RTN hi + RTN residual lo, pads = 0.
  bf16x8 waH[3], waL[3];
#pragma unroll
  for (int t = 0; t < 3; ++t) {
    u32 uh[8], ul[8];
#pragma unroll
    for (int j = 0; j < 8; ++j) {
      const int kl = g * 8 + j;
      float v = 0.f;
      if (kl < 27) {
        const int c = kl / 9, kh = (kl % 9) / 3, kw = kl % 3;
        v = wt[q15 * 81 + c * 27 + t * 9 + kh * 3 + kw];
      }
      const u32 ub = __float_as_uint(v);
      const u32 rh = ub + 0x7fffu + ((ub >> 16) & 1u);  // RTN-even (top half)
      uh[j] = rh;
      const float hi = __uint_as_float(rh & 0xffff0000u);
      const float lo = v - hi;                          // exact residual
      const u32 lb = __float_as_uint(lo);
      ul[j] = lb + 0x7fffu + ((lb >> 16) & 1u);         // RTN of residual
    }
    u32x4 hd, ld;
#pragma unroll
    for (int p = 0; p < 4; ++p) {
      hd[p] = PKHI(uh[2 * p], uh[2 * p + 1]);
      ld[p] = PKHI(ul[2 * p], ul[2 * p + 1]);
    }
    waH[t] = __builtin_bit_cast(bf16x8, hd);
    waL[t] = __builtin_bit_cast(bf16x8, ld);
  }

  const float* xb = x + ((size_t)b * CC * DD) * HW + (size_t)h * WW;

  // Prologue: planes 0,1 packed immediately; planes 2,3 raw in U0,U1.
  u32 u0[8], u1[8];
  bf16x8 f0, f1, f2;
  load_raw(xb + (size_t)0 * HW, voff, u0);
  load_raw(xb + (size_t)1 * HW, voff, u1);
  pack_hi(u0, f0);
  pack_hi(u1, f1);
  load_raw(xb + (size_t)2 * HW, voff, u0);
  load_raw(xb + (size_t)3 * HW, voff, u1);

  const f32x4 z4 = {0.f, 0.f, 0.f, 0.f};
  f32x4 mn = {INFINITY, INFINITY, INFINITY, INFINITY};

  // dz = 0..17: period-6 (U parity x F rotation); step dz packs plane dz+2
  // and prefetches plane dz+4.
#pragma clang loop unroll(disable)
  for (int dzb = 0; dzb < 18; dzb += 6) {
    dz_step(xb, dzb + 4, voff, waH, waL, u0, f0, f1, f2, z4, mn);
    dz_step(xb, dzb + 5, voff, waH, waL, u1, f1, f2, f0, z4, mn);
    dz_step(xb, dzb + 6, voff, waH, waL, u0, f2, f0, f1, z4, mn);
    dz_step(xb, dzb + 7, voff, waH, waL, u1, f0, f1, f2, z4, mn);
    dz_step(xb, dzb + 8, voff, waH, waL, u0, f1, f2, f0, z4, mn);
    dz_step(xb, dzb + 9, voff, waH, waL, u1, f2, f0, f1, z4, mn);
  }
  // Tail dz = 18..21 (prefetch clamped to plane 23).
  dz_step(xb, 22, voff, waH, waL, u0, f0, f1, f2, z4, mn);
  dz_step(xb, 23, voff, waH, waL, u1, f1, f2, f0, z4, mn);
  dz_step(xb, 23, voff, waH, waL, u0, f2, f0, f1, z4, mn);
  dz_step(xb, 23, voff, waH, waL, u1, f0, f1, f2, z4, mn);

  // Softmax over oc for this lane's pixel: 4 in-lane regs (oc = g*4+r) +
  // lanes sharing q15 across g (xor 16, 32).
  float mx = fmaxf(fmaxf(mn.x, mn.y), fmaxf(mn.z, mn.w));
  mx = fmaxf(mx, __shfl_xor(mx, 16));
  mx = fmaxf(mx, __shfl_xor(mx, 32));
  const float e0 = __expf(mn.x - mx);
  const float e1 = __expf(mn.y - mx);
  const float e2 = __expf(mn.z - mx);
  const float e3 = __expf(mn.w - mx);
  float s = (e0 + e1) + (e2 + e3);
  s += __shfl_xor(s, 16);
  s += __shfl_xor(s, 32);
  const float inv = 1.f / s;

  // Store: out[b][oc = g*4+r][h][w0+q15]; 16 consecutive pixels per (g,r).
  float* ob = out + (((size_t)(b * OCC + g * 4) * HOUT + h) * WOUT) + w0 + q15;
  const size_t os = (size_t)HOUT * WOUT;
  ob[0 * os] = e0 * inv;
  ob[1 * os] = e1 * inv;
  ob[2 * os] = e2 * inv;
  ob[3 * os] = e3 * inv;
}

extern "C" void kernel_launch(void* const* d_in, const int* in_sizes, int n_in,
                              void* d_out, int out_size, void* d_ws, size_t ws_size,
                              hipStream_t stream) {
  const float* x = (const float*)d_in[0];
  const float* wt = (const float*)d_in[1];
  float* out = (float*)d_out;

  dim3 grid(BB, HOUT, 2);   // b (XCD-pinned), h, w-tile-pair
  dim3 block(256, 1, 1);    // 4 waves = 4 w-tiles
  conv_min_softmax_mfma<<<grid, block, 0, stream>>>(x, wt, out);
}

// Round 21
// 30.618 us; speedup vs baseline: 1.3347x; 1.1051x over previous
//
#include <hip/hip_runtime.h>
#include <math.h>

// Problem constants
#define BB 8
#define CC 3
#define DD 24
#define HH 128
#define WW 128
#define HW (HH * WW)
#define OCC 16
#define HOUT 126
#define WOUT 126

typedef short bf16x8 __attribute__((ext_vector_type(8)));   // 4 VGPR
typedef float f32x4 __attribute__((ext_vector_type(4)));
typedef unsigned int u32;
typedef u32 u32x4 __attribute__((ext_vector_type(4)));

#define MFMA(a, b, c) __builtin_amdgcn_mfma_f32_16x16x32_bf16((a), (b), (c), 0, 0, 0)
// Pack the top halves of two f32 (a=even slot, c=odd slot) into one dword:
// result = (a>>16) | (c & 0xffff0000)  ==  v_perm_b32(hi=c, lo=a, 0x07060302)
#define PKHI(a, c) __builtin_amdgcn_perm((c), (a), 0x07060302u)

// Issue the 8 raw fp32 loads of one depth-plane's im2col slots (no pack).
__device__ __forceinline__ void load_raw(const float* __restrict__ xp,
                                         const int (&voff)[8], u32 (&u)[8]) {
#pragma unroll
  for (int j = 0; j < 8; ++j) u[j] = __float_as_uint(xp[voff[j]]);
}

// Pack 8 raw fp32 into ONE truncated-bf16 fragment: 4 v_perm_b32 total.
__device__ __forceinline__ void pack_hi(const u32 (&u)[8], bf16x8& fh) {
  u32x4 hd;
#pragma unroll
  for (int p = 0; p < 4; ++p) hd[p] = PKHI(u[2 * p], u[2 * p + 1]);
  fh = __builtin_bit_cast(bf16x8, hd);
}

// One dz step. ROUND 21 = r20's proven distance-2 schedule (pack FIRST,
// then reload the SAME buffer -> anti-dependency keeps order; prefetch
// distance = 2 full steps) with SINGLE-TERM x SINGLE-TERM numerics:
// x = trunc-bf16 (4-perm pack), w = RTN-bf16 (prologue), 3 MFMAs/step.
// Evidence: r17 (w-RTN only) and r18/r20 (x-trunc only) each measured
// absmax exactly 2^-9; combined expected ~2^-8 = 3.9e-3 < 6.5e-3 threshold.
__device__ __forceinline__ void dz_step(const float* __restrict__ xb, int pnext,
                                        const int (&voff)[8],
                                        const bf16x8 (&wa)[3],
                                        u32 (&ubuf)[8],
                                        bf16x8& fa, bf16x8& fb, bf16x8& fc,
                                        const f32x4& z4, f32x4& mn) {
  pack_hi(ubuf, fc);                             // consume plane dz+2
  load_raw(xb + (size_t)pnext * HW, voff, ubuf); // prefetch plane dz+4
  f32x4 acc = MFMA(wa[0], fa, z4);
  acc = MFMA(wa[1], fb, acc);
  acc = MFMA(wa[2], fc, acc);
  mn.x = fminf(mn.x, acc.x);
  mn.y = fminf(mn.y, acc.y);
  mn.z = fminf(mn.z, acc.z);
  mn.w = fminf(mn.w, acc.w);
}

// 256-thread blocks = 4 independent waves, wave wv handles w-tile
// wti = blockIdx.z*4+wv. Implicit-GEMM per wave: C[oc=16][px=16] via
// mfma_f32_16x16x32_bf16, A = weights (oc x K, single-term RTN-bf16),
// B = im2col (K x px, single-term trunc-bf16, 4-perm pack). K-tile t =
// kd-plane, k_local = c*9+kh*3+kw (27 real + 5 pad; pads zeroed on A
// side). Plane rotation F0..F2 reuses 2/3 fragments per dz; raw
// double-buffer U0/U1 (parity) holds plane dz+2 at step entry, reloaded
// with dz+4 after pack (distance-2). C/D layout: col=lane&15=pixel,
// row=(lane>>4)*4+reg=oc (m89-verified, r15-validated).
__global__ __launch_bounds__(256) void conv_min_softmax_mfma(
    const float* __restrict__ x, const float* __restrict__ wt,
    float* __restrict__ out) {
  const int tid = threadIdx.x;
  const int lane = tid & 63;
  const int wv = tid >> 6;            // wave id 0..3
  const int q15 = lane & 15;          // pixel (B col) and oc (A row)
  const int g = lane >> 4;            // k-slot group
  const int b = blockIdx.x;
  const int h = blockIdx.y;
  const int wti = blockIdx.z * 4 + wv;
  const int w0 = (wti == 7) ? 110 : wti * 16;  // overlap last tile (no OOB)

  // Per-lane k-slot decode: k_local = g*8+j -> (c,kh,kw); pads -> offset 0.
  int voff[8];
#pragma unroll
  for (int j = 0; j < 8; ++j) {
    const int kl = g * 8 + j;
    if (kl < 27) {
      const int c = kl / 9, kh = (kl % 9) / 3, kw = kl % 3;
      voff[j] = c * DD * HW + kh * WW + (w0 + q15 + kw);
    } else {
      voff[j] = 0;  // finite dummy; A-side weight is 0 for pad slots
    }
  }

  // Weight fragments (A), per kd-tile t: single-term RTN bf16, pads = 0.
  bf16x8 wa[3];
#pragma unroll
  for (int t = 0; t < 3; ++t) {
    u32 u[8];
#pragma unroll
    for (int j = 0; j < 8; ++j) {
      const int kl = g * 8 + j;
      float v = 0.f;
      if (kl < 27) {
        const int c = kl / 9, kh = (kl % 9) / 3, kw = kl % 3;
        v = wt[q15 * 81 + c * 27 + t * 9 + kh * 3 + kw];
      }
      const u32 ub = __float_as_uint(v);
      u[j] = ub + 0x7fffu + ((ub >> 16) & 1u);  // round-to-nearest-even bf16
    }
    u32x4 hd;
#pragma unroll
    for (int p = 0; p < 4; ++p) hd[p] = PKHI(u[2 * p], u[2 * p + 1]);
    wa[t] = __builtin_bit_cast(bf16x8, hd);
  }

  const float* xb = x + ((size_t)b * CC * DD) * HW + (size_t)h * WW;

  // Prologue: planes 0,1 packed immediately; planes 2,3 raw in U0,U1.
  u32 u0[8], u1[8];
  bf16x8 f0, f1, f2;
  load_raw(xb + (size_t)0 * HW, voff, u0);
  load_raw(xb + (size_t)1 * HW, voff, u1);
  pack_hi(u0, f0);
  pack_hi(u1, f1);
  load_raw(xb + (size_t)2 * HW, voff, u0);
  load_raw(xb + (size_t)3 * HW, voff, u1);

  const f32x4 z4 = {0.f, 0.f, 0.f, 0.f};
  f32x4 mn = {INFINITY, INFINITY, INFINITY, INFINITY};

  // dz = 0..17: period-6 (U parity x F rotation); step dz packs plane dz+2
  // and prefetches plane dz+4.
#pragma clang loop unroll(disable)
  for (int dzb = 0; dzb < 18; dzb += 6) {
    dz_step(xb, dzb + 4, voff, wa, u0, f0, f1, f2, z4, mn);
    dz_step(xb, dzb + 5, voff, wa, u1, f1, f2, f0, z4, mn);
    dz_step(xb, dzb + 6, voff, wa, u0, f2, f0, f1, z4, mn);
    dz_step(xb, dzb + 7, voff, wa, u1, f0, f1, f2, z4, mn);
    dz_step(xb, dzb + 8, voff, wa, u0, f1, f2, f0, z4, mn);
    dz_step(xb, dzb + 9, voff, wa, u1, f2, f0, f1, z4, mn);
  }
  // Tail dz = 18..21 (prefetch clamped to plane 23).
  dz_step(xb, 22, voff, wa, u0, f0, f1, f2, z4, mn);
  dz_step(xb, 23, voff, wa, u1, f1, f2, f0, z4, mn);
  dz_step(xb, 23, voff, wa, u0, f2, f0, f1, z4, mn);
  dz_step(xb, 23, voff, wa, u1, f0, f1, f2, z4, mn);

  // Softmax over oc for this lane's pixel: 4 in-lane regs (oc = g*4+r) +
  // lanes sharing q15 across g (xor 16, 32).
  float mx = fmaxf(fmaxf(mn.x, mn.y), fmaxf(mn.z, mn.w));
  mx = fmaxf(mx, __shfl_xor(mx, 16));
  mx = fmaxf(mx, __shfl_xor(mx, 32));
  const float e0 = __expf(mn.x - mx);
  const float e1 = __expf(mn.y - mx);
  const float e2 = __expf(mn.z - mx);
  const float e3 = __expf(mn.w - mx);
  float s = (e0 + e1) + (e2 + e3);
  s += __shfl_xor(s, 16);
  s += __shfl_xor(s, 32);
  const float inv = 1.f / s;

  // Store: out[b][oc = g*4+r][h][w0+q15]; 16 consecutive pixels per (g,r).
  float* ob = out + (((size_t)(b * OCC + g * 4) * HOUT + h) * WOUT) + w0 + q15;
  const size_t os = (size_t)HOUT * WOUT;
  ob[0 * os] = e0 * inv;
  ob[1 * os] = e1 * inv;
  ob[2 * os] = e2 * inv;
  ob[3 * os] = e3 * inv;
}

extern "C" void kernel_launch(void* const* d_in, const int* in_sizes, int n_in,
                              void* d_out, int out_size, void* d_ws, size_t ws_size,
                              hipStream_t stream) {
  const float* x = (const float*)d_in[0];
  const float* wt = (const float*)d_in[1];
  float* out = (float*)d_out;

  dim3 grid(BB, HOUT, 2);   // b (XCD-pinned), h, w-tile-pair
  dim3 block(256, 1, 1);    // 4 waves = 4 w-tiles
  conv_min_softmax_mfma<<<grid, block, 0, stream>>>(x, wt, out);
}

// Round 22
// 29.627 us; speedup vs baseline: 1.3794x; 1.0334x over previous
//
#include <hip/hip_runtime.h>
#include <math.h>

// Problem constants
#define BB 8
#define CC 3
#define DD 24
#define HH 128
#define WW 128
#define HW (HH * WW)
#define OCC 16
#define HOUT 126
#define WOUT 126

typedef short bf16x8 __attribute__((ext_vector_type(8)));   // 4 VGPR
typedef float f32x4 __attribute__((ext_vector_type(4)));
typedef unsigned int u32;
typedef u32 u32x4 __attribute__((ext_vector_type(4)));

#define MFMA(a, b, c) __builtin_amdgcn_mfma_f32_16x16x32_bf16((a), (b), (c), 0, 0, 0)
// Pack the top halves of two f32 (a=even slot, c=odd slot) into one dword:
// result = (a>>16) | (c & 0xffff0000)  ==  v_perm_b32(hi=c, lo=a, 0x07060302)
#define PKHI(a, c) __builtin_amdgcn_perm((c), (a), 0x07060302u)

// Issue the 8 raw fp32 loads of one depth-plane's im2col slots (no pack).
__device__ __forceinline__ void load_raw(const float* __restrict__ xp,
                                         const int (&voff)[8], u32 (&u)[8]) {
#pragma unroll
  for (int j = 0; j < 8; ++j) u[j] = __float_as_uint(xp[voff[j]]);
}

// Pack 8 raw fp32 into ONE truncated-bf16 fragment: 4 v_perm_b32 total.
__device__ __forceinline__ void pack_hi(const u32 (&u)[8], bf16x8& fh) {
  u32x4 hd;
#pragma unroll
  for (int p = 0; p < 4; ++p) hd[p] = PKHI(u[2 * p], u[2 * p + 1]);
  fh = __builtin_bit_cast(bf16x8, hd);
}

// One dz step (r20/r21 distance-2 schedule): pack plane dz+2 from ubuf,
// reload the SAME buffer with plane dz+4 (anti-dependency keeps order),
// 3 MFMAs (K = 3 planes x 27), running min.
__device__ __forceinline__ void dz_step(const float* __restrict__ xb, int pnext,
                                        const int (&voff)[8],
                                        const bf16x8 (&wa)[3],
                                        u32 (&ubuf)[8],
                                        bf16x8& fa, bf16x8& fb, bf16x8& fc,
                                        const f32x4& z4, f32x4& mn) {
  pack_hi(ubuf, fc);                             // consume plane dz+2
  load_raw(xb + (size_t)pnext * HW, voff, ubuf); // prefetch plane dz+4
  f32x4 acc = MFMA(wa[0], fa, z4);
  acc = MFMA(wa[1], fb, acc);
  acc = MFMA(wa[2], fc, acc);
  mn.x = fminf(mn.x, acc.x);
  mn.y = fminf(mn.y, acc.y);
  mn.z = fminf(mn.z, acc.z);
  mn.w = fminf(mn.w, acc.w);
}

// Tail variant: no prefetch (r22: removes 2 redundant plane-23 reloads).
__device__ __forceinline__ void dz_step_nl(const int (&voff)[8],
                                           const bf16x8 (&wa)[3],
                                           u32 (&ubuf)[8],
                                           bf16x8& fa, bf16x8& fb, bf16x8& fc,
                                           const f32x4& z4, f32x4& mn) {
  pack_hi(ubuf, fc);
  f32x4 acc = MFMA(wa[0], fa, z4);
  acc = MFMA(wa[1], fb, acc);
  acc = MFMA(wa[2], fc, acc);
  mn.x = fminf(mn.x, acc.x);
  mn.y = fminf(mn.y, acc.y);
  mn.z = fminf(mn.z, acc.z);
  mn.w = fminf(mn.w, acc.w);
}

// ROUND 22: row-aligned k-slot bijection. slot(g,j): g<3 -> (row=j, kw=g)
// with row=(c,kh)=(j/3, j%3) covering rows 0..7; g=3 -> j<3: row 8
// (c2,kh2) at kw=j, j>=3: pad (A-side weight 0). Each load instruction j
// now touches ~2-3 cache lines (one row's 19 consecutive floats for g<3 +
// one row-8 line) instead of 5-7 under the old c*9+kh*3+kw map where g
// spanned 4 different rows -> TA work per step roughly halves. A and B use
// the same bijection so the MFMA contraction is unchanged (k-order
// permutation only). Numerics (x trunc-bf16, w RTN-bf16, 3 MFMA/step,
// absmax 2^-8) and the distance-2 schedule are r21-verbatim.
__global__ __launch_bounds__(256) void conv_min_softmax_mfma(
    const float* __restrict__ x, const float* __restrict__ wt,
    float* __restrict__ out) {
  const int tid = threadIdx.x;
  const int lane = tid & 63;
  const int wv = tid >> 6;            // wave id 0..3
  const int q15 = lane & 15;          // pixel (B col) and oc (A row)
  const int g = lane >> 4;            // kw (g<3) / row-8+pad group (g=3)
  const int b = blockIdx.x;
  const int h = blockIdx.y;
  const int wti = blockIdx.z * 4 + wv;
  const int w0 = (wti == 7) ? 110 : wti * 16;  // overlap last tile (no OOB)

  // Per-lane k-slot offsets (j compile-time -> no div/mod chains).
  int voff[8];
#pragma unroll
  for (int j = 0; j < 8; ++j) {
    const int rowbase = (j / 3) * DD * HW + (j % 3) * WW;  // row j = (c,kh)
    if (g < 3) {
      voff[j] = rowbase + (w0 + q15 + g);
    } else {
      voff[j] = (j < 3) ? (2 * DD * HW + 2 * WW + (w0 + q15 + j)) : 0;
    }
  }

  // Weight fragments (A), per kd-tile t: single-term RTN bf16, same slot
  // bijection as B; pads (g=3, j>=3) = 0.
  bf16x8 wa[3];
#pragma unroll
  for (int t = 0; t < 3; ++t) {
    u32 u[8];
#pragma unroll
    for (int j = 0; j < 8; ++j) {
      float v = 0.f;
      if (g < 3) {
        // (c=j/3, kd=t, kh=j%3, kw=g)
        v = wt[q15 * 81 + (j / 3) * 27 + t * 9 + (j % 3) * 3 + g];
      } else if (j < 3) {
        // row 8: (c=2, kd=t, kh=2, kw=j)
        v = wt[q15 * 81 + 2 * 27 + t * 9 + 2 * 3 + j];
      }
      const u32 ub = __float_as_uint(v);
      u[j] = ub + 0x7fffu + ((ub >> 16) & 1u);  // round-to-nearest-even bf16
    }
    u32x4 hd;
#pragma unroll
    for (int p = 0; p < 4; ++p) hd[p] = PKHI(u[2 * p], u[2 * p + 1]);
    wa[t] = __builtin_bit_cast(bf16x8, hd);
  }

  const float* xb = x + ((size_t)b * CC * DD) * HW + (size_t)h * WW;

  // Prologue: planes 0,1 packed immediately; planes 2,3 raw in U0,U1.
  u32 u0[8], u1[8];
  bf16x8 f0, f1, f2;
  load_raw(xb + (size_t)0 * HW, voff, u0);
  load_raw(xb + (size_t)1 * HW, voff, u1);
  pack_hi(u0, f0);
  pack_hi(u1, f1);
  load_raw(xb + (size_t)2 * HW, voff, u0);
  load_raw(xb + (size_t)3 * HW, voff, u1);

  const f32x4 z4 = {0.f, 0.f, 0.f, 0.f};
  f32x4 mn = {INFINITY, INFINITY, INFINITY, INFINITY};

  // dz = 0..17: period-6 (U parity x F rotation); step dz packs plane dz+2
  // and prefetches plane dz+4.
#pragma clang loop unroll(disable)
  for (int dzb = 0; dzb < 18; dzb += 6) {
    dz_step(xb, dzb + 4, voff, wa, u0, f0, f1, f2, z4, mn);
    dz_step(xb, dzb + 5, voff, wa, u1, f1, f2, f0, z4, mn);
    dz_step(xb, dzb + 6, voff, wa, u0, f2, f0, f1, z4, mn);
    dz_step(xb, dzb + 7, voff, wa, u1, f0, f1, f2, z4, mn);
    dz_step(xb, dzb + 8, voff, wa, u0, f1, f2, f0, z4, mn);
    dz_step(xb, dzb + 9, voff, wa, u1, f2, f0, f1, z4, mn);
  }
  // Tail dz = 18..21; last two steps have no remaining planes to prefetch.
  dz_step(xb, 22, voff, wa, u0, f0, f1, f2, z4, mn);
  dz_step(xb, 23, voff, wa, u1, f1, f2, f0, z4, mn);
  dz_step_nl(voff, wa, u0, f2, f0, f1, z4, mn);
  dz_step_nl(voff, wa, u1, f0, f1, f2, z4, mn);

  // Softmax over oc for this lane's pixel: 4 in-lane regs (oc = g*4+r) +
  // lanes sharing q15 across g (xor 16, 32).
  float mx = fmaxf(fmaxf(mn.x, mn.y), fmaxf(mn.z, mn.w));
  mx = fmaxf(mx, __shfl_xor(mx, 16));
  mx = fmaxf(mx, __shfl_xor(mx, 32));
  const float e0 = __expf(mn.x - mx);
  const float e1 = __expf(mn.y - mx);
  const float e2 = __expf(mn.z - mx);
  const float e3 = __expf(mn.w - mx);
  float s = (e0 + e1) + (e2 + e3);
  s += __shfl_xor(s, 16);
  s += __shfl_xor(s, 32);
  const float inv = 1.f / s;

  // Store: out[b][oc = g*4+r][h][w0+q15]; 16 consecutive pixels per (g,r).
  float* ob = out + (((size_t)(b * OCC + g * 4) * HOUT + h) * WOUT) + w0 + q15;
  const size_t os = (size_t)HOUT * WOUT;
  ob[0 * os] = e0 * inv;
  ob[1 * os] = e1 * inv;
  ob[2 * os] = e2 * inv;
  ob[3 * os] = e3 * inv;
}

extern "C" void kernel_launch(void* const* d_in, const int* in_sizes, int n_in,
                              void* d_out, int out_size, void* d_ws, size_t ws_size,
                              hipStream_t stream) {
  const float* x = (const float*)d_in[0];
  const float* wt = (const float*)d_in[1];
  float* out = (float*)d_out;

  dim3 grid(BB, HOUT, 2);   // b (XCD-pinned), h, w-tile-pair
  dim3 block(256, 1, 1);    // 4 waves = 4 w-tiles
  conv_min_softmax_mfma<<<grid, block, 0, stream>>>(x, wt, out);
}